// Round 5
// baseline (564.862 us; speedup 1.0000x reference)
//
#include <hip/hip_runtime.h>

// CRF NLL via MFMA-batched exp-space forward recursion.
//
// Kernel 1 (crf_alpha): 16 batches per wave, 32 waves total.
//   E^T[p][b] recursion: D[t',b] = sum_p W[t'][p] * E[p][b]  (8x mfma 16x16x32 bf16,
//   A = W = exp(trans) constant in 8 register fragments), then
//   E_next[t'][b] = D[t'][b] * exp(feats[b][s][t']).
//   - D (C/D layout: batch=lane&15, tag=16*mt+4*(lane>>4)+reg) -> next step's
//     B operand (batch=lane&15, k=8*(lane>>4)+j) via LDS round trip
//     (store [batch][tag] bf16, row stride 80 -> ds_read_b128 per K-chunk).
//   - per-batch freeze for ragged lengths via divergent if (exec mask):
//     frozen lanes stop updating E/e-regs; their B column only feeds their
//     own (discarded) D column.
//   - per-COLUMN power-of-2 renorm every 8 steps (cross-quad shfl max of
//     exponents; exact: scale commutes with bf16 rounding), C tracks log2.
//   - feats loaded per-lane directly in consume layout, 4-step register ring.
// Kernel 2 (crf_gold): one wave per batch, lane-parallel gold path score,
//   out[b] = alpha - gold.

#define TT 64

typedef __attribute__((ext_vector_type(8))) short short8;
typedef __attribute__((ext_vector_type(4))) float floatx4;
typedef __attribute__((ext_vector_type(4))) int intx4;
typedef __attribute__((ext_vector_type(2))) int intx2;

#define MFMA(A, B, C) __builtin_amdgcn_mfma_f32_16x16x32_bf16((A), (B), (C), 0, 0, 0)

__device__ __forceinline__ unsigned short f2bf(float f) {
  unsigned u = __builtin_bit_cast(unsigned, f);
  return (unsigned short)((u + 0x8000u) >> 16);  // round-half-up to bf16
}
__device__ __forceinline__ int pack2(float a, float b) {
  return (int)(((unsigned)f2bf(a)) | (((unsigned)f2bf(b)) << 16));
}
__device__ __forceinline__ float shflx_f(float v, int m) {
  return __shfl_xor(v, m, 64);
}

// A fragment: W''[m = row][k = coloff + j], 8 consecutive p.
__device__ __forceinline__ short8 make_a(const float* trans, int row, int coloff) {
  const float* ap = trans + row * TT + coloff;
  floatx4 u0 = *(const floatx4*)ap;
  floatx4 u1 = *(const floatx4*)(ap + 4);
  short8 a;
  a[0] = (short)f2bf(__expf(u0.x)); a[1] = (short)f2bf(__expf(u0.y));
  a[2] = (short)f2bf(__expf(u0.z)); a[3] = (short)f2bf(__expf(u0.w));
  a[4] = (short)f2bf(__expf(u1.x)); a[5] = (short)f2bf(__expf(u1.y));
  a[6] = (short)f2bf(__expf(u1.z)); a[7] = (short)f2bf(__expf(u1.w));
  return a;
}

__device__ __forceinline__ void store_e(unsigned short* s_E, int n, int q,
                                        const floatx4& e0, const floatx4& e1,
                                        const floatx4& e2, const floatx4& e3) {
  int* w = (int*)s_E;
  intx2 t;
  t.x = pack2(e0.x, e0.y); t.y = pack2(e0.z, e0.w);
  *(intx2*)(w + n * 40 + 2 * q) = t;
  t.x = pack2(e1.x, e1.y); t.y = pack2(e1.z, e1.w);
  *(intx2*)(w + n * 40 + 8 + 2 * q) = t;
  t.x = pack2(e2.x, e2.y); t.y = pack2(e2.z, e2.w);
  *(intx2*)(w + n * 40 + 16 + 2 * q) = t;
  t.x = pack2(e3.x, e3.y); t.y = pack2(e3.z, e3.w);
  *(intx2*)(w + n * 40 + 24 + 2 * q) = t;
}

__device__ __forceinline__ void load_feats(floatx4& r0, floatx4& r1, floatx4& r2,
                                           floatx4& r3, const float* fp, int srow,
                                           int q) {
  const float* p = fp + (size_t)srow * TT + 4 * q;
  r0 = *(const floatx4*)(p);
  r1 = *(const floatx4*)(p + 16);
  r2 = *(const floatx4*)(p + 32);
  r3 = *(const floatx4*)(p + 48);
}

__device__ __forceinline__ void crf_step(
    int s_, int len_col, int n, int q, unsigned short* s_E,
    const short8& a00, const short8& a01, const short8& a10, const short8& a11,
    const short8& a20, const short8& a21, const short8& a30, const short8& a31,
    floatx4& e0, floatx4& e1, floatx4& e2, floatx4& e3,
    const floatx4& r0, const floatx4& r1, const floatx4& r2, const floatx4& r3) {
  if (s_ < len_col) {  // divergence IS the per-batch freeze
    const int* sEr = (const int*)s_E;
    short8 bf0 = __builtin_bit_cast(short8, *(const intx4*)(sEr + n * 40 + 4 * q));
    short8 bf1 = __builtin_bit_cast(short8, *(const intx4*)(sEr + n * 40 + 16 + 4 * q));
    floatx4 z = {0.f, 0.f, 0.f, 0.f};
    floatx4 d0 = MFMA(a00, bf0, z); d0 = MFMA(a01, bf1, d0);
    floatx4 d1 = MFMA(a10, bf0, z); d1 = MFMA(a11, bf1, d1);
    floatx4 d2 = MFMA(a20, bf0, z); d2 = MFMA(a21, bf1, d2);
    floatx4 d3 = MFMA(a30, bf0, z); d3 = MFMA(a31, bf1, d3);
    e0.x = d0.x * __expf(r0.x); e0.y = d0.y * __expf(r0.y);
    e0.z = d0.z * __expf(r0.z); e0.w = d0.w * __expf(r0.w);
    e1.x = d1.x * __expf(r1.x); e1.y = d1.y * __expf(r1.y);
    e1.z = d1.z * __expf(r1.z); e1.w = d1.w * __expf(r1.w);
    e2.x = d2.x * __expf(r2.x); e2.y = d2.y * __expf(r2.y);
    e2.z = d2.z * __expf(r2.z); e2.w = d2.w * __expf(r2.w);
    e3.x = d3.x * __expf(r3.x); e3.y = d3.y * __expf(r3.y);
    e3.z = d3.z * __expf(r3.z); e3.w = d3.w * __expf(r3.w);
    store_e(s_E, n, q, e0, e1, e2, e3);
  }
}

__device__ __forceinline__ void renorm8(floatx4& e0, floatx4& e1, floatx4& e2,
                                        floatx4& e3, int& C, int n, int q,
                                        unsigned short* s_E) {
  float m = fmaxf(fmaxf(fmaxf(e0.x, e0.y), fmaxf(e0.z, e0.w)),
                  fmaxf(fmaxf(e1.x, e1.y), fmaxf(e1.z, e1.w)));
  m = fmaxf(m, fmaxf(fmaxf(fmaxf(e2.x, e2.y), fmaxf(e2.z, e2.w)),
                     fmaxf(fmaxf(e3.x, e3.y), fmaxf(e3.z, e3.w))));
  m = fmaxf(m, shflx_f(m, 16));  // reduce across the 4 quads of this column
  m = fmaxf(m, shflx_f(m, 32));
  int k = (int)(__builtin_bit_cast(unsigned, m) >> 23) - 127;  // m > 0 always
  C += k;
  float sc = __builtin_bit_cast(float, (unsigned)(127 - k) << 23);
  e0 *= sc; e1 *= sc; e2 *= sc; e3 *= sc;
  store_e(s_E, n, q, e0, e1, e2, e3);  // keep stored bf16 consistent (exact pow2)
}

__global__ __launch_bounds__(64, 1) void crf_alpha_kernel(
    const float* __restrict__ feats, const int* __restrict__ lengths,
    const float* __restrict__ trans, const int* __restrict__ p_start,
    const int* __restrict__ p_stop, float* __restrict__ out, int B, int S) {
  const int lane = threadIdx.x;
  const int n = lane & 15;   // batch column
  const int q = lane >> 4;   // quad
  const int b0 = blockIdx.x * 16;

  __shared__ unsigned short s_E[16 * 80];  // E^T bf16, [batch][tag], stride 80

  const int start = *p_start;
  const int stop = *p_stop;

  const int bidx = (b0 + n < B) ? (b0 + n) : (B - 1);
  int len_col = (b0 + n < B) ? lengths[bidx] : 0;
  int wl = len_col;
  wl = max(wl, __shfl_xor(wl, 1, 64));
  wl = max(wl, __shfl_xor(wl, 2, 64));
  wl = max(wl, __shfl_xor(wl, 4, 64));
  wl = max(wl, __shfl_xor(wl, 8, 64));
  const int ngroups = (wl + 7) >> 3;

  // zero + init E0 = delta(start) for every batch
  {
    int* z = (int*)s_E;
    for (int i = lane; i < 16 * 40; i += 64) z[i] = 0;
    if (lane < 16) s_E[lane * 80 + start] = (unsigned short)0x3F80;  // bf16 1.0
  }

  // A fragments: W''[m][k] = exp(trans[16*mt + m][32*c + k]) (constant)
  short8 a00 = make_a(trans, n,      8 * q);
  short8 a01 = make_a(trans, n,      32 + 8 * q);
  short8 a10 = make_a(trans, 16 + n, 8 * q);
  short8 a11 = make_a(trans, 16 + n, 32 + 8 * q);
  short8 a20 = make_a(trans, 32 + n, 8 * q);
  short8 a21 = make_a(trans, 32 + n, 32 + 8 * q);
  short8 a30 = make_a(trans, 48 + n, 8 * q);
  short8 a31 = make_a(trans, 48 + n, 32 + 8 * q);

  // fp32 E in D-layout: e_mt component r = E[tag=16*mt+4*q+r][batch=n]
  floatx4 e0, e1, e2, e3;
  {
    int t0 = 4 * q;
    e0.x = (t0 + 0 == start) ? 1.f : 0.f; e0.y = (t0 + 1 == start) ? 1.f : 0.f;
    e0.z = (t0 + 2 == start) ? 1.f : 0.f; e0.w = (t0 + 3 == start) ? 1.f : 0.f;
    int t1 = 16 + t0;
    e1.x = (t1 + 0 == start) ? 1.f : 0.f; e1.y = (t1 + 1 == start) ? 1.f : 0.f;
    e1.z = (t1 + 2 == start) ? 1.f : 0.f; e1.w = (t1 + 3 == start) ? 1.f : 0.f;
    int t2 = 32 + t0;
    e2.x = (t2 + 0 == start) ? 1.f : 0.f; e2.y = (t2 + 1 == start) ? 1.f : 0.f;
    e2.z = (t2 + 2 == start) ? 1.f : 0.f; e2.w = (t2 + 3 == start) ? 1.f : 0.f;
    int t3 = 48 + t0;
    e3.x = (t3 + 0 == start) ? 1.f : 0.f; e3.y = (t3 + 1 == start) ? 1.f : 0.f;
    e3.z = (t3 + 2 == start) ? 1.f : 0.f; e3.w = (t3 + 3 == start) ? 1.f : 0.f;
  }
  int C = 0;

  const float* fp = feats + (size_t)bidx * S * TT;  // this lane's batch row base

  // 4-step feats register ring, loaded directly in consume layout
  floatx4 rA0, rA1, rA2, rA3, rB0, rB1, rB2, rB3;
  floatx4 rC0, rC1, rC2, rC3, rD0, rD1, rD2, rD3;
  load_feats(rA0, rA1, rA2, rA3, fp, 0 < S ? 0 : S - 1, q);
  load_feats(rB0, rB1, rB2, rB3, fp, 1 < S ? 1 : S - 1, q);
  load_feats(rC0, rC1, rC2, rC3, fp, 2 < S ? 2 : S - 1, q);
  load_feats(rD0, rD1, rD2, rD3, fp, 3 < S ? 3 : S - 1, q);

  int sbase = 0;
#pragma unroll 1
  for (int grp = 0; grp < ngroups; ++grp) {
#define STEP_R(SOFF, R0, R1, R2, R3)                                          \
  crf_step(sbase + (SOFF), len_col, n, q, s_E, a00, a01, a10, a11, a20, a21,  \
           a30, a31, e0, e1, e2, e3, R0, R1, R2, R3);                         \
  {                                                                           \
    int nx = sbase + (SOFF) + 4;                                              \
    load_feats(R0, R1, R2, R3, fp, nx < S ? nx : S - 1, q);                   \
  }
    STEP_R(0, rA0, rA1, rA2, rA3)
    STEP_R(1, rB0, rB1, rB2, rB3)
    STEP_R(2, rC0, rC1, rC2, rC3)
    STEP_R(3, rD0, rD1, rD2, rD3)
    STEP_R(4, rA0, rA1, rA2, rA3)
    STEP_R(5, rB0, rB1, rB2, rB3)
    STEP_R(6, rC0, rC1, rC2, rC3)
    STEP_R(7, rD0, rD1, rD2, rD3)
#undef STEP_R
    renorm8(e0, e1, e2, e3, C, n, q, s_E);
    sbase += 8;
  }

  // alpha[column] = C*ln2 + log( sum_t E[t] * exp(trans[stop][t]) )
  const float* wp = trans + stop * TT + 4 * q;
  float sum =
      e0.x * __expf(wp[0]) + e0.y * __expf(wp[1]) +
      e0.z * __expf(wp[2]) + e0.w * __expf(wp[3]) +
      e1.x * __expf(wp[16]) + e1.y * __expf(wp[17]) +
      e1.z * __expf(wp[18]) + e1.w * __expf(wp[19]) +
      e2.x * __expf(wp[32]) + e2.y * __expf(wp[33]) +
      e2.z * __expf(wp[34]) + e2.w * __expf(wp[35]) +
      e3.x * __expf(wp[48]) + e3.y * __expf(wp[49]) +
      e3.z * __expf(wp[50]) + e3.w * __expf(wp[51]);
  sum += shflx_f(sum, 16);
  sum += shflx_f(sum, 32);
  float alpha = __logf(sum) + (float)C * 0.6931471805599453f;
  if (lane < 16 && b0 + n < B) out[b0 + n] = alpha;
}

__global__ __launch_bounds__(64, 1) void crf_gold_kernel(
    const float* __restrict__ feats, const int* __restrict__ tags,
    const int* __restrict__ lengths, const float* __restrict__ trans,
    const int* __restrict__ p_start, const int* __restrict__ p_stop,
    float* __restrict__ out, int S) {
  const int lane = threadIdx.x;
  const int b = blockIdx.x;
  __shared__ float s_trans[TT * TT];
  for (int i = lane * 4; i < TT * TT; i += 256) {
    *reinterpret_cast<float4*>(&s_trans[i]) =
        *reinterpret_cast<const float4*>(trans + i);
  }
  __syncthreads();
  const int start = *p_start;
  const int stop = *p_stop;
  const int len = lengths[b];
  const int* tb = tags + (size_t)b * S;
  const float* fb = feats + (size_t)b * S * TT;
  float gs = 0.f;
#pragma unroll 1
  for (int s0 = 0; s0 < len; s0 += 64) {
    int si = s0 + lane;
    if (si < len) {
      int t = tb[si];
      int tp = si ? tb[si - 1] : start;
      gs += s_trans[t * TT + tp] + fb[(size_t)si * TT + t];
    }
  }
#pragma unroll
  for (int off = 32; off >= 1; off >>= 1) gs += __shfl_xor(gs, off, 64);
  float alpha = out[b];  // written by crf_alpha_kernel (same stream, ordered)
  float gold = gs + s_trans[stop * TT + tb[len - 1]];
  if (lane == 0) out[b] = alpha - gold;
}

extern "C" void kernel_launch(void* const* d_in, const int* in_sizes, int n_in,
                              void* d_out, int out_size, void* d_ws, size_t ws_size,
                              hipStream_t stream) {
  const float* feats = (const float*)d_in[0];
  const int* tags = (const int*)d_in[1];
  const int* lengths = (const int*)d_in[2];
  // d_in[3] = masks: unused; masks[b,s] == (s < lengths[b]) by construction
  const float* trans = (const float*)d_in[4];
  const int* p_start = (const int*)d_in[5];
  const int* p_stop = (const int*)d_in[6];
  float* out = (float*)d_out;

  int B = in_sizes[2];
  int S = in_sizes[1] / B;
  int blocks1 = (B + 15) / 16;
  crf_alpha_kernel<<<blocks1, 64, 0, stream>>>(feats, lengths, trans, p_start,
                                               p_stop, out, B, S);
  crf_gold_kernel<<<B, 64, 0, stream>>>(feats, tags, lengths, trans, p_start,
                                        p_stop, out, S);
}

// Round 6
// 482.607 us; speedup vs baseline: 1.1704x; 1.1704x over previous
//
#include <hip/hip_runtime.h>

// CRF NLL via MFMA-batched exp-space forward recursion.
//
// Kernel 1 (crf_alpha): 16 batches per wave, 32 waves total.
//   D[t',n] = sum_p W[t',p] * E[p,n]  (8x mfma_f32_16x16x32_bf16, A = exp(trans)
//   constant in 8 register fragments), E_next[t',n] = D[t',n] * exp(feats[n,s,t']).
//   D (C layout) -> next step's B operand via LDS round trip, bf16 [batch][tag].
//   R6 chain surgery (R5 was 950 cyc/step, all exposed latency):
//    - row stride 72 shorts (36 dwords): b128 reads start at bank 4(n+q) ->
//      uniform, 16B aligned; writes 2-way max (was 4-way every write, 1.04M conflicts).
//    - exp(feats) staged one full step ahead (xC regs) off the dependency chain.
//    - fp32->bf16 pack via single v_perm_b32 (truncation) instead of ~44 shift/or.
//   Freeze for ragged lengths via divergent if (validated R5: exec-masked MFMA
//   confines stale columns). Per-column pow2 renorm every 8 steps, C tracks log2.
// Kernel 2 (crf_gold): one wave per batch, lane-parallel gold path score,
//   out[b] = alpha - gold.

#define TT 64
#define ROWD 36  // dwords per batch row in s_E (72 shorts)

typedef __attribute__((ext_vector_type(8))) short short8;
typedef __attribute__((ext_vector_type(4))) float floatx4;
typedef __attribute__((ext_vector_type(4))) int intx4;
typedef __attribute__((ext_vector_type(2))) int intx2;

#define MFMA(A, B, C) __builtin_amdgcn_mfma_f32_16x16x32_bf16((A), (B), (C), 0, 0, 0)

__device__ __forceinline__ unsigned short f2bf(float f) {  // RN-ish (setup only)
  unsigned u = __builtin_bit_cast(unsigned, f);
  return (unsigned short)((u + 0x8000u) >> 16);
}
// one-instruction truncating pack: result = [bf(b) | bf(a)] (a in low 16)
__device__ __forceinline__ int pack2t(float a, float b) {
  return (int)__builtin_amdgcn_perm(__builtin_bit_cast(unsigned, b),
                                    __builtin_bit_cast(unsigned, a), 0x07060302u);
}
__device__ __forceinline__ float shflx_f(float v, int m) { return __shfl_xor(v, m, 64); }
__device__ __forceinline__ floatx4 expf4(floatx4 v) {
  floatx4 r;
  r.x = __expf(v.x); r.y = __expf(v.y); r.z = __expf(v.z); r.w = __expf(v.w);
  return r;
}

// A fragment: W[m = row][k = coloff + j], 8 consecutive p.
__device__ __forceinline__ short8 make_a(const float* trans, int row, int coloff) {
  const float* ap = trans + row * TT + coloff;
  floatx4 u0 = *(const floatx4*)ap;
  floatx4 u1 = *(const floatx4*)(ap + 4);
  short8 a;
  a[0] = (short)f2bf(__expf(u0.x)); a[1] = (short)f2bf(__expf(u0.y));
  a[2] = (short)f2bf(__expf(u0.z)); a[3] = (short)f2bf(__expf(u0.w));
  a[4] = (short)f2bf(__expf(u1.x)); a[5] = (short)f2bf(__expf(u1.y));
  a[6] = (short)f2bf(__expf(u1.z)); a[7] = (short)f2bf(__expf(u1.w));
  return a;
}

__device__ __forceinline__ void store_e(unsigned short* s_E, int n, int q,
                                        const floatx4& e0, const floatx4& e1,
                                        const floatx4& e2, const floatx4& e3) {
  int* w = (int*)s_E;
  intx2 t;
  t.x = pack2t(e0.x, e0.y); t.y = pack2t(e0.z, e0.w);
  *(intx2*)(w + n * ROWD + 2 * q) = t;
  t.x = pack2t(e1.x, e1.y); t.y = pack2t(e1.z, e1.w);
  *(intx2*)(w + n * ROWD + 8 + 2 * q) = t;
  t.x = pack2t(e2.x, e2.y); t.y = pack2t(e2.z, e2.w);
  *(intx2*)(w + n * ROWD + 16 + 2 * q) = t;
  t.x = pack2t(e3.x, e3.y); t.y = pack2t(e3.z, e3.w);
  *(intx2*)(w + n * ROWD + 24 + 2 * q) = t;
}

__device__ __forceinline__ void load_feats(floatx4& r0, floatx4& r1, floatx4& r2,
                                           floatx4& r3, const float* fp, int srow,
                                           int q) {
  const float* p = fp + (size_t)srow * TT + 4 * q;
  r0 = *(const floatx4*)(p);
  r1 = *(const floatx4*)(p + 16);
  r2 = *(const floatx4*)(p + 32);
  r3 = *(const floatx4*)(p + 48);
}

__device__ __forceinline__ void crf_step(
    int s_, int len_col, int n, int q, unsigned short* s_E,
    const short8& a00, const short8& a01, const short8& a10, const short8& a11,
    const short8& a20, const short8& a21, const short8& a30, const short8& a31,
    floatx4& e0, floatx4& e1, floatx4& e2, floatx4& e3,
    const floatx4& x0, const floatx4& x1, const floatx4& x2, const floatx4& x3) {
  if (s_ < len_col) {  // divergence IS the per-batch freeze (R5-validated)
    const int* sEr = (const int*)s_E;
    short8 bf0 = __builtin_bit_cast(short8, *(const intx4*)(sEr + n * ROWD + 4 * q));
    short8 bf1 = __builtin_bit_cast(short8, *(const intx4*)(sEr + n * ROWD + 16 + 4 * q));
    floatx4 z = {0.f, 0.f, 0.f, 0.f};
    floatx4 d0 = MFMA(a00, bf0, z); d0 = MFMA(a01, bf1, d0);
    floatx4 d1 = MFMA(a10, bf0, z); d1 = MFMA(a11, bf1, d1);
    floatx4 d2 = MFMA(a20, bf0, z); d2 = MFMA(a21, bf1, d2);
    floatx4 d3 = MFMA(a30, bf0, z); d3 = MFMA(a31, bf1, d3);
    e0 = d0 * x0;  // x = exp(feats), staged one step ahead (off-chain)
    e1 = d1 * x1;
    e2 = d2 * x2;
    e3 = d3 * x3;
    store_e(s_E, n, q, e0, e1, e2, e3);
  }
}

__device__ __forceinline__ void renorm8(floatx4& e0, floatx4& e1, floatx4& e2,
                                        floatx4& e3, int& C, int n, int q,
                                        unsigned short* s_E) {
  float m = fmaxf(fmaxf(fmaxf(e0.x, e0.y), fmaxf(e0.z, e0.w)),
                  fmaxf(fmaxf(e1.x, e1.y), fmaxf(e1.z, e1.w)));
  m = fmaxf(m, fmaxf(fmaxf(fmaxf(e2.x, e2.y), fmaxf(e2.z, e2.w)),
                     fmaxf(fmaxf(e3.x, e3.y), fmaxf(e3.z, e3.w))));
  m = fmaxf(m, shflx_f(m, 16));  // reduce across the 4 quads of this column
  m = fmaxf(m, shflx_f(m, 32));
  int k = (int)(__builtin_bit_cast(unsigned, m) >> 23) - 127;  // m > 0 always
  C += k;
  float sc = __builtin_bit_cast(float, (unsigned)(127 - k) << 23);
  e0 *= sc; e1 *= sc; e2 *= sc; e3 *= sc;
  store_e(s_E, n, q, e0, e1, e2, e3);  // exact pow2: stored bf16 stays consistent
}

__global__ __launch_bounds__(64, 1) void crf_alpha_kernel(
    const float* __restrict__ feats, const int* __restrict__ lengths,
    const float* __restrict__ trans, const int* __restrict__ p_start,
    const int* __restrict__ p_stop, float* __restrict__ out, int B, int S) {
  const int lane = threadIdx.x;
  const int n = lane & 15;   // batch column
  const int q = lane >> 4;   // quad
  const int b0 = blockIdx.x * 16;

  __shared__ unsigned short s_E[16 * 2 * ROWD];  // bf16 E^T [batch][tag], stride 72

  const int start = *p_start;
  const int stop = *p_stop;

  const int bidx = (b0 + n < B) ? (b0 + n) : (B - 1);
  int len_col = (b0 + n < B) ? lengths[bidx] : 0;
  int wl = len_col;
  wl = max(wl, __shfl_xor(wl, 1, 64));
  wl = max(wl, __shfl_xor(wl, 2, 64));
  wl = max(wl, __shfl_xor(wl, 4, 64));
  wl = max(wl, __shfl_xor(wl, 8, 64));
  const int ngroups = (wl + 7) >> 3;

  // zero + init E0 = delta(start) for every batch
  {
    int* z = (int*)s_E;
    for (int i = lane; i < 16 * ROWD; i += 64) z[i] = 0;
    if (lane < 16) s_E[lane * 2 * ROWD + start] = (unsigned short)0x3F80;  // bf16 1.0
  }

  // A fragments: W[m][k] = exp(trans[16*mt + m][32*c + 8q + j]) (constant)
  short8 a00 = make_a(trans, n,      8 * q);
  short8 a01 = make_a(trans, n,      32 + 8 * q);
  short8 a10 = make_a(trans, 16 + n, 8 * q);
  short8 a11 = make_a(trans, 16 + n, 32 + 8 * q);
  short8 a20 = make_a(trans, 32 + n, 8 * q);
  short8 a21 = make_a(trans, 32 + n, 32 + 8 * q);
  short8 a30 = make_a(trans, 48 + n, 8 * q);
  short8 a31 = make_a(trans, 48 + n, 32 + 8 * q);

  // fp32 E in D-layout: e_mt component r = E[tag=16*mt+4*q+r][batch=n]
  floatx4 e0, e1, e2, e3;
  {
    int t0 = 4 * q;
    e0.x = (t0 + 0 == start) ? 1.f : 0.f; e0.y = (t0 + 1 == start) ? 1.f : 0.f;
    e0.z = (t0 + 2 == start) ? 1.f : 0.f; e0.w = (t0 + 3 == start) ? 1.f : 0.f;
    int t1 = 16 + t0;
    e1.x = (t1 + 0 == start) ? 1.f : 0.f; e1.y = (t1 + 1 == start) ? 1.f : 0.f;
    e1.z = (t1 + 2 == start) ? 1.f : 0.f; e1.w = (t1 + 3 == start) ? 1.f : 0.f;
    int t2 = 32 + t0;
    e2.x = (t2 + 0 == start) ? 1.f : 0.f; e2.y = (t2 + 1 == start) ? 1.f : 0.f;
    e2.z = (t2 + 2 == start) ? 1.f : 0.f; e2.w = (t2 + 3 == start) ? 1.f : 0.f;
    int t3 = 48 + t0;
    e3.x = (t3 + 0 == start) ? 1.f : 0.f; e3.y = (t3 + 1 == start) ? 1.f : 0.f;
    e3.z = (t3 + 2 == start) ? 1.f : 0.f; e3.w = (t3 + 3 == start) ? 1.f : 0.f;
  }
  int C = 0;

  const float* fp = feats + (size_t)bidx * S * TT;  // this lane's batch row base

  // xC = exp(feats row s) staged one step ahead; ring rA..rD = raw rows s+1..s+4
  floatx4 xC0, xC1, xC2, xC3;
  floatx4 rA0, rA1, rA2, rA3, rB0, rB1, rB2, rB3;
  floatx4 rC0, rC1, rC2, rC3, rD0, rD1, rD2, rD3;
  load_feats(xC0, xC1, xC2, xC3, fp, 0, q);
  xC0 = expf4(xC0); xC1 = expf4(xC1); xC2 = expf4(xC2); xC3 = expf4(xC3);
  load_feats(rA0, rA1, rA2, rA3, fp, 1 < S ? 1 : S - 1, q);
  load_feats(rB0, rB1, rB2, rB3, fp, 2 < S ? 2 : S - 1, q);
  load_feats(rC0, rC1, rC2, rC3, fp, 3 < S ? 3 : S - 1, q);
  load_feats(rD0, rD1, rD2, rD3, fp, 4 < S ? 4 : S - 1, q);

  int sbase = 0;
#pragma unroll 1
  for (int grp = 0; grp < ngroups; ++grp) {
#define STEP_R(SOFF, R0, R1, R2, R3)                                          \
  crf_step(sbase + (SOFF), len_col, n, q, s_E, a00, a01, a10, a11, a20, a21,  \
           a30, a31, e0, e1, e2, e3, xC0, xC1, xC2, xC3);                     \
  xC0 = expf4(R0); xC1 = expf4(R1); xC2 = expf4(R2); xC3 = expf4(R3);         \
  {                                                                           \
    int nx = sbase + (SOFF) + 5;                                              \
    load_feats(R0, R1, R2, R3, fp, nx < S ? nx : S - 1, q);                   \
  }
    STEP_R(0, rA0, rA1, rA2, rA3)
    STEP_R(1, rB0, rB1, rB2, rB3)
    STEP_R(2, rC0, rC1, rC2, rC3)
    STEP_R(3, rD0, rD1, rD2, rD3)
    STEP_R(4, rA0, rA1, rA2, rA3)
    STEP_R(5, rB0, rB1, rB2, rB3)
    STEP_R(6, rC0, rC1, rC2, rC3)
    STEP_R(7, rD0, rD1, rD2, rD3)
#undef STEP_R
    renorm8(e0, e1, e2, e3, C, n, q, s_E);
    sbase += 8;
  }

  // alpha[column] = C*ln2 + log( sum_t E[t] * exp(trans[stop][t]) )
  const float* wp = trans + stop * TT + 4 * q;
  float sum =
      e0.x * __expf(wp[0]) + e0.y * __expf(wp[1]) +
      e0.z * __expf(wp[2]) + e0.w * __expf(wp[3]) +
      e1.x * __expf(wp[16]) + e1.y * __expf(wp[17]) +
      e1.z * __expf(wp[18]) + e1.w * __expf(wp[19]) +
      e2.x * __expf(wp[32]) + e2.y * __expf(wp[33]) +
      e2.z * __expf(wp[34]) + e2.w * __expf(wp[35]) +
      e3.x * __expf(wp[48]) + e3.y * __expf(wp[49]) +
      e3.z * __expf(wp[50]) + e3.w * __expf(wp[51]);
  sum += shflx_f(sum, 16);
  sum += shflx_f(sum, 32);
  float alpha = __logf(sum) + (float)C * 0.6931471805599453f;
  if (lane < 16 && b0 + n < B) out[b0 + n] = alpha;
}

__global__ __launch_bounds__(64, 1) void crf_gold_kernel(
    const float* __restrict__ feats, const int* __restrict__ tags,
    const int* __restrict__ lengths, const float* __restrict__ trans,
    const int* __restrict__ p_start, const int* __restrict__ p_stop,
    float* __restrict__ out, int S) {
  const int lane = threadIdx.x;
  const int b = blockIdx.x;
  __shared__ float s_trans[TT * TT];
  for (int i = lane * 4; i < TT * TT; i += 256) {
    *reinterpret_cast<float4*>(&s_trans[i]) =
        *reinterpret_cast<const float4*>(trans + i);
  }
  __syncthreads();
  const int start = *p_start;
  const int stop = *p_stop;
  const int len = lengths[b];
  const int* tb = tags + (size_t)b * S;
  const float* fb = feats + (size_t)b * S * TT;
  float gs = 0.f;
#pragma unroll 1
  for (int s0 = 0; s0 < len; s0 += 64) {
    int si = s0 + lane;
    if (si < len) {
      int t = tb[si];
      int tp = si ? tb[si - 1] : start;
      gs += s_trans[t * TT + tp] + fb[(size_t)si * TT + t];
    }
  }
#pragma unroll
  for (int off = 32; off >= 1; off >>= 1) gs += __shfl_xor(gs, off, 64);
  float alpha = out[b];  // written by crf_alpha_kernel (same stream, ordered)
  float gold = gs + s_trans[stop * TT + tb[len - 1]];
  if (lane == 0) out[b] = alpha - gold;
}

extern "C" void kernel_launch(void* const* d_in, const int* in_sizes, int n_in,
                              void* d_out, int out_size, void* d_ws, size_t ws_size,
                              hipStream_t stream) {
  const float* feats = (const float*)d_in[0];
  const int* tags = (const int*)d_in[1];
  const int* lengths = (const int*)d_in[2];
  // d_in[3] = masks: unused; masks[b,s] == (s < lengths[b]) by construction
  const float* trans = (const float*)d_in[4];
  const int* p_start = (const int*)d_in[5];
  const int* p_stop = (const int*)d_in[6];
  float* out = (float*)d_out;

  int B = in_sizes[2];
  int S = in_sizes[1] / B;
  int blocks1 = (B + 15) / 16;
  crf_alpha_kernel<<<blocks1, 64, 0, stream>>>(feats, lengths, trans, p_start,
                                               p_stop, out, B, S);
  crf_gold_kernel<<<B, 64, 0, stream>>>(feats, tags, lengths, trans, p_start,
                                        p_stop, out, S);
}

// Round 7
// 459.676 us; speedup vs baseline: 1.2288x; 1.0499x over previous
//
#include <hip/hip_runtime.h>

// CRF NLL via MFMA-batched exp-space forward recursion.
//
// Kernel 1 (crf_alpha): 16 batches per wave, 32 waves total.
//   D[t',n] = sum_p W[t',p] * E[p,n]  (8x mfma_f32_16x16x32_bf16, A = exp(trans)
//   constant in 8 register fragments), E_next[t',n] = D[t',n] * exp(feats[n,s,t']).
//   D (C layout) -> next step's B operand via LDS round trip, bf16 [batch][tag],
//   row stride 72 shorts (reads bank-uniform-ish, writes 2-way).
//
//   R7: the per-step `if (s < len_col)` guard (R5/R6) wrapped the whole
//   dependency chain in an exec-mask branch region, blocking the scheduler
//   from hoisting exp/load staging into the LDS-read latency shadow
//   (R6 = 745 cyc/step, ~600 exposed latency). Now:
//    - hot loop is BRANCH-FREE; every column runs to the window max
//      (finished columns compute bounded garbage: renorm keeps E finite).
//    - alpha is captured on the fly in a rare divergent branch when
//      s+1 == len_col (<=16 hits per wave): dot with precomputed stop
//      weights, 2 intra-column shfls (all 4 lanes share the condition).
//    - exp(feats) staging (xA/xB double bank) + ring loads sit between the
//      LDS-read issue and the MFMAs to fill the read latency.
// Kernel 2 (crf_gold): one wave per batch, out[b] = alpha - gold.

#define TT 64
#define ROWD 36  // dwords per batch row in s_E (72 shorts)

typedef __attribute__((ext_vector_type(8))) short short8;
typedef __attribute__((ext_vector_type(4))) float floatx4;
typedef __attribute__((ext_vector_type(4))) int intx4;
typedef __attribute__((ext_vector_type(2))) int intx2;

#define MFMA(A, B, C) __builtin_amdgcn_mfma_f32_16x16x32_bf16((A), (B), (C), 0, 0, 0)

__device__ __forceinline__ unsigned short f2bf(float f) {  // RN-ish (setup only)
  unsigned u = __builtin_bit_cast(unsigned, f);
  return (unsigned short)((u + 0x8000u) >> 16);
}
// one-instruction truncating pack: result = [bf(b) | bf(a)] (a in low 16)
__device__ __forceinline__ int pack2t(float a, float b) {
  return (int)__builtin_amdgcn_perm(__builtin_bit_cast(unsigned, b),
                                    __builtin_bit_cast(unsigned, a), 0x07060302u);
}
__device__ __forceinline__ float shflx_f(float v, int m) { return __shfl_xor(v, m, 64); }
__device__ __forceinline__ floatx4 expf4(floatx4 v) {
  floatx4 r;
  r.x = __expf(v.x); r.y = __expf(v.y); r.z = __expf(v.z); r.w = __expf(v.w);
  return r;
}

// A fragment: W[m = row][k = coloff + j], 8 consecutive p.
__device__ __forceinline__ short8 make_a(const float* trans, int row, int coloff) {
  const float* ap = trans + row * TT + coloff;
  floatx4 u0 = *(const floatx4*)ap;
  floatx4 u1 = *(const floatx4*)(ap + 4);
  short8 a;
  a[0] = (short)f2bf(__expf(u0.x)); a[1] = (short)f2bf(__expf(u0.y));
  a[2] = (short)f2bf(__expf(u0.z)); a[3] = (short)f2bf(__expf(u0.w));
  a[4] = (short)f2bf(__expf(u1.x)); a[5] = (short)f2bf(__expf(u1.y));
  a[6] = (short)f2bf(__expf(u1.z)); a[7] = (short)f2bf(__expf(u1.w));
  return a;
}

__device__ __forceinline__ void store_e(unsigned short* s_E, int n, int q,
                                        const floatx4& e0, const floatx4& e1,
                                        const floatx4& e2, const floatx4& e3) {
  int* w = (int*)s_E;
  intx2 t;
  t.x = pack2t(e0.x, e0.y); t.y = pack2t(e0.z, e0.w);
  *(intx2*)(w + n * ROWD + 2 * q) = t;
  t.x = pack2t(e1.x, e1.y); t.y = pack2t(e1.z, e1.w);
  *(intx2*)(w + n * ROWD + 8 + 2 * q) = t;
  t.x = pack2t(e2.x, e2.y); t.y = pack2t(e2.z, e2.w);
  *(intx2*)(w + n * ROWD + 16 + 2 * q) = t;
  t.x = pack2t(e3.x, e3.y); t.y = pack2t(e3.z, e3.w);
  *(intx2*)(w + n * ROWD + 24 + 2 * q) = t;
}

__device__ __forceinline__ void load_feats(floatx4& r0, floatx4& r1, floatx4& r2,
                                           floatx4& r3, const float* fp, int srow,
                                           int q) {
  const float* p = fp + (size_t)srow * TT + 4 * q;
  r0 = *(const floatx4*)(p);
  r1 = *(const floatx4*)(p + 16);
  r2 = *(const floatx4*)(p + 32);
  r3 = *(const floatx4*)(p + 48);
}

__device__ __forceinline__ void renorm8(floatx4& e0, floatx4& e1, floatx4& e2,
                                        floatx4& e3, int& C, int n, int q,
                                        unsigned short* s_E) {
  float m = fmaxf(fmaxf(fmaxf(e0.x, e0.y), fmaxf(e0.z, e0.w)),
                  fmaxf(fmaxf(e1.x, e1.y), fmaxf(e1.z, e1.w)));
  m = fmaxf(m, fmaxf(fmaxf(fmaxf(e2.x, e2.y), fmaxf(e2.z, e2.w)),
                     fmaxf(fmaxf(e3.x, e3.y), fmaxf(e3.z, e3.w))));
  m = fmaxf(m, shflx_f(m, 16));  // reduce across the 4 quads of this column
  m = fmaxf(m, shflx_f(m, 32));
  int k = (int)(__builtin_bit_cast(unsigned, m) >> 23) - 127;  // m > 0 always
  C += k;
  float sc = __builtin_bit_cast(float, (unsigned)(127 - k) << 23);
  e0 *= sc; e1 *= sc; e2 *= sc; e3 *= sc;
  store_e(s_E, n, q, e0, e1, e2, e3);  // exact pow2: stored bf16 stays consistent
}

__global__ __launch_bounds__(64, 1) void crf_alpha_kernel(
    const float* __restrict__ feats, const int* __restrict__ lengths,
    const float* __restrict__ trans, const int* __restrict__ p_start,
    const int* __restrict__ p_stop, float* __restrict__ out, int B, int S) {
  const int lane = threadIdx.x;
  const int n = lane & 15;   // batch column
  const int q = lane >> 4;   // quad
  const int b0 = blockIdx.x * 16;

  __shared__ __align__(16) unsigned short s_E[16 * 2 * ROWD];

  const int start = *p_start;
  const int stop = *p_stop;

  const int bidx = (b0 + n < B) ? (b0 + n) : (B - 1);
  const int len_col = (b0 + n < B) ? lengths[bidx] : 1;
  int wl = len_col;
  wl = max(wl, __shfl_xor(wl, 1, 64));
  wl = max(wl, __shfl_xor(wl, 2, 64));
  wl = max(wl, __shfl_xor(wl, 4, 64));
  wl = max(wl, __shfl_xor(wl, 8, 64));
  const int ngroups = (wl + 7) >> 3;

  // zero + init E0 = delta(start) for every batch (single wave: DS in-order,
  // no barrier needed)
  {
    int* z = (int*)s_E;
    for (int i = lane; i < 16 * ROWD; i += 64) z[i] = 0;
    if (lane < 16) s_E[lane * 2 * ROWD + start] = (unsigned short)0x3F80;  // bf16 1.0
  }

  // A fragments: W[m][k] = exp(trans[16*mt + m][32*c + 8q + j]) (constant)
  short8 a00 = make_a(trans, n,      8 * q);
  short8 a01 = make_a(trans, n,      32 + 8 * q);
  short8 a10 = make_a(trans, 16 + n, 8 * q);
  short8 a11 = make_a(trans, 16 + n, 32 + 8 * q);
  short8 a20 = make_a(trans, 32 + n, 8 * q);
  short8 a21 = make_a(trans, 32 + n, 32 + 8 * q);
  short8 a30 = make_a(trans, 48 + n, 8 * q);
  short8 a31 = make_a(trans, 48 + n, 32 + 8 * q);

  // stop weights in the same lane layout as e0..e3
  floatx4 wsv0, wsv1, wsv2, wsv3;
  {
    const float* wp = trans + stop * TT + 4 * q;
    wsv0.x = __expf(wp[0]);  wsv0.y = __expf(wp[1]);
    wsv0.z = __expf(wp[2]);  wsv0.w = __expf(wp[3]);
    wsv1.x = __expf(wp[16]); wsv1.y = __expf(wp[17]);
    wsv1.z = __expf(wp[18]); wsv1.w = __expf(wp[19]);
    wsv2.x = __expf(wp[32]); wsv2.y = __expf(wp[33]);
    wsv2.z = __expf(wp[34]); wsv2.w = __expf(wp[35]);
    wsv3.x = __expf(wp[48]); wsv3.y = __expf(wp[49]);
    wsv3.z = __expf(wp[50]); wsv3.w = __expf(wp[51]);
  }

  // fp32 E in D-layout: e_mt component r = E[tag=16*mt+4*q+r][batch=n]
  floatx4 e0, e1, e2, e3;
  {
    int t0 = 4 * q;
    e0.x = (t0 + 0 == start) ? 1.f : 0.f; e0.y = (t0 + 1 == start) ? 1.f : 0.f;
    e0.z = (t0 + 2 == start) ? 1.f : 0.f; e0.w = (t0 + 3 == start) ? 1.f : 0.f;
    int t1 = 16 + t0;
    e1.x = (t1 + 0 == start) ? 1.f : 0.f; e1.y = (t1 + 1 == start) ? 1.f : 0.f;
    e1.z = (t1 + 2 == start) ? 1.f : 0.f; e1.w = (t1 + 3 == start) ? 1.f : 0.f;
    int t2 = 32 + t0;
    e2.x = (t2 + 0 == start) ? 1.f : 0.f; e2.y = (t2 + 1 == start) ? 1.f : 0.f;
    e2.z = (t2 + 2 == start) ? 1.f : 0.f; e2.w = (t2 + 3 == start) ? 1.f : 0.f;
    int t3 = 48 + t0;
    e3.x = (t3 + 0 == start) ? 1.f : 0.f; e3.y = (t3 + 1 == start) ? 1.f : 0.f;
    e3.z = (t3 + 2 == start) ? 1.f : 0.f; e3.w = (t3 + 3 == start) ? 1.f : 0.f;
  }
  int C = 0;

  const float* fp = feats + (size_t)bidx * S * TT;

  // xA = exp(row 0) staged; ring rA..rD = raw rows 1..4; xB = second bank
  floatx4 xA0, xA1, xA2, xA3, xB0, xB1, xB2, xB3;
  floatx4 rA0, rA1, rA2, rA3, rB0, rB1, rB2, rB3;
  floatx4 rC0, rC1, rC2, rC3, rD0, rD1, rD2, rD3;
  load_feats(xA0, xA1, xA2, xA3, fp, 0, q);
  xA0 = expf4(xA0); xA1 = expf4(xA1); xA2 = expf4(xA2); xA3 = expf4(xA3);
  xB0 = xB1 = xB2 = xB3 = (floatx4){0.f, 0.f, 0.f, 0.f};
  load_feats(rA0, rA1, rA2, rA3, fp, 1 < S ? 1 : S - 1, q);
  load_feats(rB0, rB1, rB2, rB3, fp, 2 < S ? 2 : S - 1, q);
  load_feats(rC0, rC1, rC2, rC3, fp, 3 < S ? 3 : S - 1, q);
  load_feats(rD0, rD1, rD2, rD3, fp, 4 < S ? 4 : S - 1, q);

  int sbase = 0;
#pragma unroll 1
  for (int grp = 0; grp < ngroups; ++grp) {
    // STEP: branch-free hot body. Order: LDS reads issue first; exp staging +
    // ring load fill the read latency; MFMA; mul; pack+store; rare capture.
#define STEP(SOFF, R0, R1, R2, R3, XI0, XI1, XI2, XI3, XO0, XO1, XO2, XO3)    \
  {                                                                           \
    const int scur = sbase + (SOFF);                                          \
    const int* sEr = (const int*)s_E;                                         \
    short8 bf0 =                                                              \
        __builtin_bit_cast(short8, *(const intx4*)(sEr + n * ROWD + 4 * q));  \
    short8 bf1 = __builtin_bit_cast(                                          \
        short8, *(const intx4*)(sEr + n * ROWD + 16 + 4 * q));                \
    XO0 = expf4(R0); XO1 = expf4(R1); XO2 = expf4(R2); XO3 = expf4(R3);       \
    {                                                                         \
      int nx = scur + 5;                                                      \
      nx = nx < S ? nx : S - 1;                                               \
      load_feats(R0, R1, R2, R3, fp, nx, q);                                  \
    }                                                                         \
    floatx4 z = {0.f, 0.f, 0.f, 0.f};                                         \
    floatx4 d0 = MFMA(a00, bf0, z); d0 = MFMA(a01, bf1, d0);                  \
    floatx4 d1 = MFMA(a10, bf0, z); d1 = MFMA(a11, bf1, d1);                  \
    floatx4 d2 = MFMA(a20, bf0, z); d2 = MFMA(a21, bf1, d2);                  \
    floatx4 d3 = MFMA(a30, bf0, z); d3 = MFMA(a31, bf1, d3);                  \
    e0 = d0 * XI0; e1 = d1 * XI1; e2 = d2 * XI2; e3 = d3 * XI3;               \
    store_e(s_E, n, q, e0, e1, e2, e3);                                       \
    if (__builtin_expect(scur + 1 == len_col, 0)) {  /* rare capture */       \
      float sum = e0.x * wsv0.x + e0.y * wsv0.y + e0.z * wsv0.z +             \
                  e0.w * wsv0.w + e1.x * wsv1.x + e1.y * wsv1.y +             \
                  e1.z * wsv1.z + e1.w * wsv1.w + e2.x * wsv2.x +             \
                  e2.y * wsv2.y + e2.z * wsv2.z + e2.w * wsv2.w +             \
                  e3.x * wsv3.x + e3.y * wsv3.y + e3.z * wsv3.z +             \
                  e3.w * wsv3.w;                                              \
      sum += shflx_f(sum, 16); /* all 4 lanes of this column are here */      \
      sum += shflx_f(sum, 32);                                                \
      if (q == 0)                                                             \
        out[bidx] = __logf(sum) + (float)C * 0.6931471805599453f;             \
    }                                                                         \
  }
    STEP(0, rA0, rA1, rA2, rA3, xA0, xA1, xA2, xA3, xB0, xB1, xB2, xB3)
    STEP(1, rB0, rB1, rB2, rB3, xB0, xB1, xB2, xB3, xA0, xA1, xA2, xA3)
    STEP(2, rC0, rC1, rC2, rC3, xA0, xA1, xA2, xA3, xB0, xB1, xB2, xB3)
    STEP(3, rD0, rD1, rD2, rD3, xB0, xB1, xB2, xB3, xA0, xA1, xA2, xA3)
    STEP(4, rA0, rA1, rA2, rA3, xA0, xA1, xA2, xA3, xB0, xB1, xB2, xB3)
    STEP(5, rB0, rB1, rB2, rB3, xB0, xB1, xB2, xB3, xA0, xA1, xA2, xA3)
    STEP(6, rC0, rC1, rC2, rC3, xA0, xA1, xA2, xA3, xB0, xB1, xB2, xB3)
    STEP(7, rD0, rD1, rD2, rD3, xB0, xB1, xB2, xB3, xA0, xA1, xA2, xA3)
#undef STEP
    renorm8(e0, e1, e2, e3, C, n, q, s_E);
    sbase += 8;
  }
}

__global__ __launch_bounds__(64, 1) void crf_gold_kernel(
    const float* __restrict__ feats, const int* __restrict__ tags,
    const int* __restrict__ lengths, const float* __restrict__ trans,
    const int* __restrict__ p_start, const int* __restrict__ p_stop,
    float* __restrict__ out, int S) {
  const int lane = threadIdx.x;
  const int b = blockIdx.x;
  __shared__ float s_trans[TT * TT];
  for (int i = lane * 4; i < TT * TT; i += 256) {
    *reinterpret_cast<float4*>(&s_trans[i]) =
        *reinterpret_cast<const float4*>(trans + i);
  }
  __syncthreads();
  const int start = *p_start;
  const int stop = *p_stop;
  const int len = lengths[b];
  const int* tb = tags + (size_t)b * S;
  const float* fb = feats + (size_t)b * S * TT;
  float gs = 0.f;
#pragma unroll 1
  for (int s0 = 0; s0 < len; s0 += 64) {
    int si = s0 + lane;
    if (si < len) {
      int t = tb[si];
      int tp = si ? tb[si - 1] : start;
      gs += s_trans[t * TT + tp] + fb[(size_t)si * TT + t];
    }
  }
#pragma unroll
  for (int off = 32; off >= 1; off >>= 1) gs += __shfl_xor(gs, off, 64);
  float alpha = out[b];  // written by crf_alpha_kernel (same stream, ordered)
  float gold = gs + s_trans[stop * TT + tb[len - 1]];
  if (lane == 0) out[b] = alpha - gold;
}

extern "C" void kernel_launch(void* const* d_in, const int* in_sizes, int n_in,
                              void* d_out, int out_size, void* d_ws, size_t ws_size,
                              hipStream_t stream) {
  const float* feats = (const float*)d_in[0];
  const int* tags = (const int*)d_in[1];
  const int* lengths = (const int*)d_in[2];
  // d_in[3] = masks: unused; masks[b,s] == (s < lengths[b]) by construction
  const float* trans = (const float*)d_in[4];
  const int* p_start = (const int*)d_in[5];
  const int* p_stop = (const int*)d_in[6];
  float* out = (float*)d_out;

  int B = in_sizes[2];
  int S = in_sizes[1] / B;
  int blocks1 = (B + 15) / 16;
  crf_alpha_kernel<<<blocks1, 64, 0, stream>>>(feats, lengths, trans, p_start,
                                               p_stop, out, B, S);
  crf_gold_kernel<<<B, 64, 0, stream>>>(feats, tags, lengths, trans, p_start,
                                        p_stop, out, S);
}